// Round 13
// baseline (624.234 us; speedup 1.0000x reference)
//
#include <hip/hip_runtime.h>
#include <math.h>

#define LR_C 0.1f
#define WINDOW_C 10
#define NH 512
#define WAVE 64
#define ALPHA (-1.44269504088896340736f)  // -log2(e)
#define NSEG 500
#define KSWEEPS 12   // calibration at NSEG=250: K=8 -> 0.109, K=12 -> 0.0078,
                     // ratio ~0.52/sweep. NSEG=500 halves per-segment defect;
                     // binomial-bound predicts error <= same at fixed K.

__device__ __forceinline__ void gld_lds16(const void* g, void* l) {
    __builtin_amdgcn_global_load_lds((const __attribute__((address_space(1))) void*)g,
                                     (__attribute__((address_space(3))) void*)l, 16, 0, 0);
}
__device__ __forceinline__ void gld_lds4(const void* g, void* l) {
    __builtin_amdgcn_global_load_lds((const __attribute__((address_space(1))) void*)g,
                                     (__attribute__((address_space(3))) void*)l, 4, 0, 0);
}

// Scaled space: W = ALPHA*w, y_t = W[t]·x_t, h_t = 1/(1+2^{y_t}),
// W[t+1] = W[t] + h_t*cx_t,  cx_t = ALPHA*LR*r_t*x_t.
// Lookahead: y_{t+1} = u_t + h_t*d_t,  u_t = W[t]·x_{t+1},  d_t = cx_t·x_{t+1}.
__global__ void prep_kernel(const float* __restrict__ X,
                            const float* __restrict__ rewards,
                            float4* __restrict__ pk, float* __restrict__ dv,
                            int T, int Talloc) {
    int t = blockIdx.x * blockDim.x + threadIdx.x;
    if (t >= Talloc) return;
    if (t >= T) { pk[t] = make_float4(0.f, 0.f, 0.f, 0.f); dv[t] = 0.f; return; }
    int lo = t - (WINDOW_C - 1); if (lo < 0) lo = 0;
    float s = 0.0f;
    for (int k = lo; k <= t; ++k) s += rewards[k];
    float r = rewards[t] - s / (float)(t - lo + 1);
    float c = ALPHA * LR_C * r;
    float cx0 = c * X[2 * t];
    float cx1 = c * X[2 * t + 1];
    float xn0 = 0.0f, xn1 = 0.0f;
    if (t + 1 < T) { xn0 = X[2 * t + 2]; xn1 = X[2 * t + 3]; }
    pk[t] = make_float4(xn0, xn1, cx0, cx1);
    dv[t] = fmaf(cx1, xn1, cx0 * xn0);
}

// Parareal sweep. Block pair (2 blocks) per segment; 256 threads = 4 waves,
// each thread owns one hidden unit. Staging issued FIRST so its latency
// overlaps the prefix-sum prologue (32-deep unrolled -> 32 loads in flight).
// launch_bounds(256,4): 4 blocks/CU -> all 2*NSEG=1000 blocks co-resident.
template <int OUT>
__global__ __launch_bounds__(256, 4) void sweep_kernel(
    const float* __restrict__ Wg, const float* __restrict__ X,
    const float4* __restrict__ pk, const float* __restrict__ dv,
    const float* __restrict__ Dread, float* __restrict__ Dwrite,
    int sweep, int L, int Lpad, float* __restrict__ partial, int T, int TW) {
    extern __shared__ char smem[];
    float4* lpk = (float4*)smem;
    float*  ldv = (float*)(smem + 16 * (size_t)Lpad);

    const int tid  = threadIdx.x;
    const int s    = blockIdx.x >> 1;
    const int half = blockIdx.x & 1;
    const int unit = half * 256 + tid;
    const int lane = tid & 63;
    const int wv   = tid >> 6;
    const int t0   = s * L;

    // stage this segment's operand stream into LDS (issued before prologue;
    // completes while the prefix sum computes)
    for (int k = wv; k * 64 < Lpad; k += 4)
        gld_lds16(pk + t0 + k * 64 + lane, lpk + k * 64);
    for (int k = wv; k * 64 < Lpad; k += 4)
        gld_lds4(dv + t0 + k * 64 + lane, ldv + k * 64);

    float W0 = ALPHA * Wg[2 * unit];
    float W1 = ALPHA * Wg[2 * unit + 1];
    if (sweep > 0) {
        const float2* dp = (const float2*)Dread;
        float acc0[8], acc1[8];
        #pragma unroll
        for (int j = 0; j < 8; ++j) { acc0[j] = 0.f; acc1[j] = 0.f; }
        int sp = 0;
        for (; sp + 32 <= s; sp += 32) {   // 32 independent loads in flight
            float2 v[32];
            #pragma unroll
            for (int j = 0; j < 32; ++j) v[j] = dp[(size_t)(sp + j) * NH + unit];
            #pragma unroll
            for (int j = 0; j < 32; ++j) { acc0[j & 7] += v[j].x; acc1[j & 7] += v[j].y; }
        }
        for (; sp + 8 <= s; sp += 8) {
            float2 v[8];
            #pragma unroll
            for (int j = 0; j < 8; ++j) v[j] = dp[(size_t)(sp + j) * NH + unit];
            #pragma unroll
            for (int j = 0; j < 8; ++j) { acc0[j] += v[j].x; acc1[j] += v[j].y; }
        }
        for (; sp < s; ++sp) {
            float2 v = dp[(size_t)sp * NH + unit];
            acc0[0] += v.x; acc1[0] += v.y;
        }
        float t00 = 0.f, t01 = 0.f;
        #pragma unroll
        for (int j = 0; j < 8; ++j) { t00 += acc0[j]; t01 += acc1[j]; }
        W0 += t00; W1 += t01;
    }
    const float Wi0 = W0, Wi1 = W1;

    __builtin_amdgcn_s_waitcnt(0);
    __syncthreads();

    float x0 = 0.f, x1 = 0.f;
    if (t0 < T) { x0 = X[2 * t0]; x1 = X[2 * t0 + 1]; }
    float u = fmaf(W1, x1, W0 * x0);     // y at segment-local t=0
    float h = 0.f, dpv = 0.f, cxp0 = 0.f, cxp1 = 0.f;

    const int prow = half * 4 + wv;      // 0..7
    float4 pA[8], pB[8], dA[2], dB[2];
    float hh[8];

#define BODY(Pq, Dq, TT)                                                      \
    {                                                                         \
        _Pragma("unroll")                                                     \
        for (int j = 0; j < 8; ++j) {                                         \
            float y = fmaf(h, dpv, u);                                        \
            W0 = fmaf(h, cxp0, W0);                                           \
            W1 = fmaf(h, cxp1, W1);                                           \
            u = fmaf(W1, Pq[j].y, W0 * Pq[j].x);                              \
            float e = __builtin_amdgcn_exp2f(y);                              \
            h = __builtin_amdgcn_rcpf(1.0f + e);                              \
            hh[j] = h;                                                        \
            cxp0 = Pq[j].z; cxp1 = Pq[j].w; dpv = Dq[j >> 2][j & 3];          \
        }                                                                     \
        if (OUT) {                                                            \
            _Pragma("unroll")                                                 \
            for (int j = 0; j < 8; ++j) {                                     \
                float ss = hh[j];                                             \
                _Pragma("unroll")                                             \
                for (int m = 1; m < WAVE; m <<= 1) ss += __shfl_xor(ss, m, WAVE); \
                hh[j] = ss;                                                   \
            }                                                                 \
            if (lane == 0) {                                                  \
                float* pp = partial + (size_t)prow * TW + t0 + (TT);          \
                *(float4*)(pp)     = make_float4(hh[0], hh[1], hh[2], hh[3]); \
                *(float4*)(pp + 4) = make_float4(hh[4], hh[5], hh[6], hh[7]); \
            }                                                                 \
        }                                                                     \
    }

    #pragma unroll
    for (int j = 0; j < 8; ++j) pA[j] = lpk[j];
    dA[0] = *(float4*)(ldv);     dA[1] = *(float4*)(ldv + 4);
    for (int s0 = 0; s0 < L; s0 += 16) {
        #pragma unroll
        for (int j = 0; j < 8; ++j) pB[j] = lpk[s0 + 8 + j];
        dB[0] = *(float4*)(ldv + s0 + 8); dB[1] = *(float4*)(ldv + s0 + 12);
        BODY(pA, dA, s0)
        if (s0 + 16 < L) {
            #pragma unroll
            for (int j = 0; j < 8; ++j) pA[j] = lpk[s0 + 16 + j];
            dA[0] = *(float4*)(ldv + s0 + 16); dA[1] = *(float4*)(ldv + s0 + 20);
        }
        BODY(pB, dB, s0 + 8)
    }
#undef BODY

    // apply the last step's update -> W at segment end
    W0 = fmaf(h, cxp0, W0);
    W1 = fmaf(h, cxp1, W1);
    if (!OUT) {
        float2* dw = (float2*)Dwrite;
        dw[(size_t)s * NH + unit] = make_float2(W0 - Wi0, W1 - Wi1);
    }
}

__global__ void final_part(const float* __restrict__ partial,
                           float* __restrict__ out, int T, int TW) {
    int t = blockIdx.x * blockDim.x + threadIdx.x;
    if (t >= T) return;
    float s = 0.0f;
    #pragma unroll
    for (int p = 0; p < 8; ++p) s += partial[(size_t)p * TW + t];
    out[t] = s * (1.0f / (float)NH);
}

extern "C" void kernel_launch(void* const* d_in, const int* in_sizes, int n_in,
                              void* d_out, int out_size, void* d_ws, size_t ws_size,
                              hipStream_t stream) {
    const float* X       = (const float*)d_in[0];
    const float* rewards = (const float*)d_in[1];
    const float* Winit   = (const float*)d_in[2];
    float* out = (float*)d_out;
    const int T = in_sizes[1];

    const int L  = (((T + NSEG - 1) / NSEG) + 15) & ~15;  // seg length, %16==0
    const int TW = NSEG * L;                               // padded horizon
    const int Lpad = ((L + 63) >> 6) << 6;                 // staged entries
    const int Talloc = TW + Lpad + 64;                     // staging overrun room

    char* w = (char*)d_ws;
    float4* pk   = (float4*)w;                 w += 16ull * (size_t)Talloc;
    float*  dvp  = (float*)w;                  w += 4ull * (size_t)Talloc;
    float*  D0   = (float*)w;                  w += 4096ull * NSEG;
    float*  D1   = (float*)w;                  w += 4096ull * NSEG;
    float*  partial = (float*)w;               // 8 * TW floats (~3.3 MB)

    prep_kernel<<<(Talloc + 255) / 256, 256, 0, stream>>>(X, rewards, pk, dvp, T, Talloc);

    const size_t smem = (size_t)Lpad * 20;  // 16B pk + 4B dv per entry
    for (int k = 0; k < KSWEEPS; ++k) {
        float* Dr = (k & 1) ? D0 : D1;   // written by sweep k-1 (unused at k=0)
        float* Dw = (k & 1) ? D1 : D0;
        sweep_kernel<0><<<2 * NSEG, 256, smem, stream>>>(
            Winit, X, pk, dvp, Dr, Dw, k, L, Lpad, nullptr, T, TW);
    }
    float* Dlast = (KSWEEPS & 1) ? D0 : D1;
    sweep_kernel<1><<<2 * NSEG, 256, smem, stream>>>(
        Winit, X, pk, dvp, Dlast, nullptr, KSWEEPS, L, Lpad, partial, T, TW);

    final_part<<<(T + 255) / 256, 256, 0, stream>>>(partial, out, T, TW);
}

// Round 14
// 572.662 us; speedup vs baseline: 1.0901x; 1.0901x over previous
//
#include <hip/hip_runtime.h>
#include <math.h>

#define LR_C 0.1f
#define WINDOW_C 10
#define NH 512
#define WAVE 64
#define ALPHA (-1.44269504088896340736f)  // -log2(e)
#define NSEG 250
#define NSEGP 512    // padded row length for transposed D
#define KSWEEPS 12   // calibration: K=8 -> 0.109, K=12 -> 0.0078 (NSEG=250)

typedef _Float16 half_t;
typedef __fp16 fp16x2_t __attribute__((ext_vector_type(2)));

__device__ __forceinline__ void gld_lds16(const void* g, void* l) {
    __builtin_amdgcn_global_load_lds((const __attribute__((address_space(1))) void*)g,
                                     (__attribute__((address_space(3))) void*)l, 16, 0, 0);
}
__device__ __forceinline__ void gld_lds4(const void* g, void* l) {
    __builtin_amdgcn_global_load_lds((const __attribute__((address_space(1))) void*)g,
                                     (__attribute__((address_space(3))) void*)l, 4, 0, 0);
}
__device__ __forceinline__ unsigned pack_h2(float a, float b) {
    union { fp16x2_t h; unsigned u; } c;
    c.h = __builtin_amdgcn_cvt_pkrtz(a, b);
    return c.u;
}
__device__ __forceinline__ unsigned pkadd(unsigned a, unsigned b) {
    union { fp16x2_t h; unsigned u; } x, y;
    x.u = a; y.u = b;
    x.h = x.h + y.h;   // v_pk_add_f16
    return x.u;
}
__device__ __forceinline__ float lo_h(unsigned u) {
    union { unsigned short s; half_t h; } c; c.s = (unsigned short)(u & 0xffffu);
    return (float)c.h;
}
__device__ __forceinline__ float hi_h(unsigned u) {
    union { unsigned short s; half_t h; } c; c.s = (unsigned short)(u >> 16);
    return (float)c.h;
}

// Scaled space: W = ALPHA*w, y_t = W[t]·x_t, h_t = 1/(1+2^{y_t}),
// W[t+1] = W[t] + h_t*cx_t,  cx_t = ALPHA*LR*r_t*x_t.
// Lookahead: y_{t+1} = u_t + h_t*d_t,  u_t = W[t]·x_{t+1},  d_t = cx_t·x_{t+1}.
__global__ void prep_kernel(const float* __restrict__ X,
                            const float* __restrict__ rewards,
                            float4* __restrict__ pk, float* __restrict__ dv,
                            int T, int Talloc) {
    int t = blockIdx.x * blockDim.x + threadIdx.x;
    if (t >= Talloc) return;
    if (t >= T) { pk[t] = make_float4(0.f, 0.f, 0.f, 0.f); dv[t] = 0.f; return; }
    int lo = t - (WINDOW_C - 1); if (lo < 0) lo = 0;
    float s = 0.0f;
    for (int k = lo; k <= t; ++k) s += rewards[k];
    float r = rewards[t] - s / (float)(t - lo + 1);
    float c = ALPHA * LR_C * r;
    float cx0 = c * X[2 * t];
    float cx1 = c * X[2 * t + 1];
    float xn0 = 0.0f, xn1 = 0.0f;
    if (t + 1 < T) { xn0 = X[2 * t + 2]; xn1 = X[2 * t + 3]; }
    pk[t] = make_float4(xn0, xn1, cx0, cx1);
    dv[t] = fmaf(cx1, xn1, cx0 * xn0);
}

// Parareal sweep. Block pair (2 blocks) per segment; 256 threads = 4 waves,
// each thread owns one hidden unit. Delta storage is TRANSPOSED:
// Dt[comp][sp], comp = 2*unit + {0,1}, row stride NSEGP -> prefix reads are
// contiguous float4 runs. OUT=1: packed-fp16 shuffle tree + uint4 partial.
template <int OUT>
__global__ __launch_bounds__(256, 4) void sweep_kernel(
    const float* __restrict__ Wg, const float* __restrict__ X,
    const float4* __restrict__ pk, const float* __restrict__ dv,
    const float* __restrict__ DtR, float* __restrict__ DtW,
    int sweep, int L, int Lpad, unsigned* __restrict__ partialU, int T, int TW2) {
    extern __shared__ char smem[];
    float4* lpk = (float4*)smem;
    float*  ldv = (float*)(smem + 16 * (size_t)Lpad);

    const int tid  = threadIdx.x;
    const int s    = blockIdx.x >> 1;
    const int half = blockIdx.x & 1;
    const int unit = half * 256 + tid;
    const int lane = tid & 63;
    const int wv   = tid >> 6;
    const int t0   = s * L;

    // stage this segment's operand stream into LDS (issued before prologue;
    // completes while the prefix sum computes)
    for (int k = wv; k * 64 < Lpad; k += 4)
        gld_lds16(pk + t0 + k * 64 + lane, lpk + k * 64);
    for (int k = wv; k * 64 < Lpad; k += 4)
        gld_lds4(dv + t0 + k * 64 + lane, ldv + k * 64);

    float W0 = ALPHA * Wg[2 * unit];
    float W1 = ALPHA * Wg[2 * unit + 1];
    if (sweep > 0) {
        const float* r0 = DtR + (size_t)(2 * unit) * NSEGP;
        const float* r1 = r0 + NSEGP;
        float a0 = 0.f, a1 = 0.f, a2 = 0.f, a3 = 0.f;
        float b0 = 0.f, b1 = 0.f, b2 = 0.f, b3 = 0.f;
        int sp = 0;
        for (; sp + 16 <= s; sp += 16) {   // 8 x dwordx4 in flight
            const float4* p0 = (const float4*)(r0 + sp);
            const float4* p1 = (const float4*)(r1 + sp);
            float4 A0 = p0[0], A1 = p0[1], A2 = p0[2], A3 = p0[3];
            float4 B0 = p1[0], B1 = p1[1], B2 = p1[2], B3 = p1[3];
            a0 += A0.x + A0.y + A0.z + A0.w;
            a1 += A1.x + A1.y + A1.z + A1.w;
            a2 += A2.x + A2.y + A2.z + A2.w;
            a3 += A3.x + A3.y + A3.z + A3.w;
            b0 += B0.x + B0.y + B0.z + B0.w;
            b1 += B1.x + B1.y + B1.z + B1.w;
            b2 += B2.x + B2.y + B2.z + B2.w;
            b3 += B3.x + B3.y + B3.z + B3.w;
        }
        for (; sp < s; ++sp) { a0 += r0[sp]; b0 += r1[sp]; }
        W0 += (a0 + a1) + (a2 + a3);
        W1 += (b0 + b1) + (b2 + b3);
    }
    const float Wi0 = W0, Wi1 = W1;

    __builtin_amdgcn_s_waitcnt(0);
    __syncthreads();

    float x0 = 0.f, x1 = 0.f;
    if (t0 < T) { x0 = X[2 * t0]; x1 = X[2 * t0 + 1]; }
    float u = fmaf(W1, x1, W0 * x0);     // y at segment-local t=0
    float h = 0.f, dpv = 0.f, cxp0 = 0.f, cxp1 = 0.f;

    const int prow = half * 4 + wv;      // 0..7
    float4 pA[8], pB[8], dA[2], dB[2];
    float hh[8];

#define BODY(Pq, Dq, TT)                                                      \
    {                                                                         \
        _Pragma("unroll")                                                     \
        for (int j = 0; j < 8; ++j) {                                         \
            float y = fmaf(h, dpv, u);                                        \
            W0 = fmaf(h, cxp0, W0);                                           \
            W1 = fmaf(h, cxp1, W1);                                           \
            u = fmaf(W1, Pq[j].y, W0 * Pq[j].x);                              \
            float e = __builtin_amdgcn_exp2f(y);                              \
            h = __builtin_amdgcn_rcpf(1.0f + e);                              \
            hh[j] = h;                                                        \
            cxp0 = Pq[j].z; cxp1 = Pq[j].w; dpv = Dq[j >> 2][j & 3];          \
        }                                                                     \
        if (OUT) {                                                            \
            unsigned pku[4];                                                  \
            _Pragma("unroll")                                                 \
            for (int q = 0; q < 4; ++q)                                       \
                pku[q] = pack_h2(hh[2 * q], hh[2 * q + 1]);                   \
            _Pragma("unroll")                                                 \
            for (int m = 1; m < WAVE; m <<= 1) {                              \
                _Pragma("unroll")                                             \
                for (int q = 0; q < 4; ++q)                                   \
                    pku[q] = pkadd(pku[q], __shfl_xor(pku[q], m, WAVE));      \
            }                                                                 \
            if (lane == 0) {                                                  \
                uint4 st = make_uint4(pku[0], pku[1], pku[2], pku[3]);        \
                *(uint4*)(partialU + (size_t)prow * TW2 + ((t0 + (TT)) >> 1)) = st; \
            }                                                                 \
        }                                                                     \
    }

    #pragma unroll
    for (int j = 0; j < 8; ++j) pA[j] = lpk[j];
    dA[0] = *(float4*)(ldv);     dA[1] = *(float4*)(ldv + 4);
    for (int s0 = 0; s0 < L; s0 += 16) {
        #pragma unroll
        for (int j = 0; j < 8; ++j) pB[j] = lpk[s0 + 8 + j];
        dB[0] = *(float4*)(ldv + s0 + 8); dB[1] = *(float4*)(ldv + s0 + 12);
        BODY(pA, dA, s0)
        if (s0 + 16 < L) {
            #pragma unroll
            for (int j = 0; j < 8; ++j) pA[j] = lpk[s0 + 16 + j];
            dA[0] = *(float4*)(ldv + s0 + 16); dA[1] = *(float4*)(ldv + s0 + 20);
        }
        BODY(pB, dB, s0 + 8)
    }
#undef BODY

    // apply the last step's update -> W at segment end
    W0 = fmaf(h, cxp0, W0);
    W1 = fmaf(h, cxp1, W1);
    if (!OUT) {
        DtW[(size_t)(2 * unit) * NSEGP + s]     = W0 - Wi0;
        DtW[(size_t)(2 * unit + 1) * NSEGP + s] = W1 - Wi1;
    }
}

// Unpack + sum the 8 packed partial rows; one thread per t-pair.
__global__ void final_packed(const unsigned* __restrict__ pU,
                             float* __restrict__ out, int T, int TW2) {
    int p = blockIdx.x * blockDim.x + threadIdx.x;
    if (p >= (T + 1) / 2) return;
    float s0 = 0.f, s1 = 0.f;
    #pragma unroll
    for (int r = 0; r < 8; ++r) {
        unsigned v = pU[(size_t)r * TW2 + p];
        s0 += lo_h(v);
        s1 += hi_h(v);
    }
    const float inv = 1.0f / (float)NH;
    out[2 * p] = s0 * inv;
    if (2 * p + 1 < T) out[2 * p + 1] = s1 * inv;
}

extern "C" void kernel_launch(void* const* d_in, const int* in_sizes, int n_in,
                              void* d_out, int out_size, void* d_ws, size_t ws_size,
                              hipStream_t stream) {
    const float* X       = (const float*)d_in[0];
    const float* rewards = (const float*)d_in[1];
    const float* Winit   = (const float*)d_in[2];
    float* out = (float*)d_out;
    const int T = in_sizes[1];

    const int L  = (((T + NSEG - 1) / NSEG) + 15) & ~15;  // seg length, %16==0
    const int TW = NSEG * L;                               // padded horizon
    const int TW2 = TW / 2;                                // t-pairs
    const int Lpad = ((L + 63) >> 6) << 6;                 // staged entries
    const int Talloc = TW + Lpad + 64;                     // staging overrun room

    char* w = (char*)d_ws;
    float4*   pk   = (float4*)w;               w += 16ull * (size_t)Talloc;
    float*    dvp  = (float*)w;                w += 4ull * (size_t)Talloc;
    float*    Dt0  = (float*)w;                w += 4ull * 1024 * NSEGP;   // 2 MB
    float*    Dt1  = (float*)w;                w += 4ull * 1024 * NSEGP;   // 2 MB
    unsigned* partialU = (unsigned*)w;         // 8 * TW2 u32 (~1.6 MB)

    prep_kernel<<<(Talloc + 255) / 256, 256, 0, stream>>>(X, rewards, pk, dvp, T, Talloc);

    const size_t smem = (size_t)Lpad * 20;  // 16B pk + 4B dv per entry
    for (int k = 0; k < KSWEEPS; ++k) {
        float* Dr = (k & 1) ? Dt0 : Dt1;   // written by sweep k-1 (unused at k=0)
        float* Dw = (k & 1) ? Dt1 : Dt0;
        sweep_kernel<0><<<2 * NSEG, 256, smem, stream>>>(
            Winit, X, pk, dvp, Dr, Dw, k, L, Lpad, nullptr, T, TW2);
    }
    float* Dlast = (KSWEEPS & 1) ? Dt0 : Dt1;
    sweep_kernel<1><<<2 * NSEG, 256, smem, stream>>>(
        Winit, X, pk, dvp, Dlast, nullptr, KSWEEPS, L, Lpad, partialU, T, TW2);

    final_packed<<<((T + 1) / 2 + 255) / 256, 256, 0, stream>>>(partialU, out, T, TW2);
}